// Round 15
// baseline (517.807 us; speedup 1.0000x reference)
//
#include <hip/hip_runtime.h>
#include <hip/hip_bf16.h>
#include <math.h>

#define BB 4
#define LF 257      // NTOK+1
#define MR 1028     // BB*LF
#define DMODEL 384
#define DIN 768
#define NST 16
#define DTR 24
#define XDB 56      // DTR + 2*N
#define POSROW 128
#define CL 16       // scan chunk length (R12 lesson: CL=8 doubles hpart traffic)
#define NC 17       // ceil(LF/CL)
#define NKC 12      // xp_k split-K chunks (64 wide, single K64 stage each)

typedef __attribute__((ext_vector_type(8))) short short8;
typedef __attribute__((ext_vector_type(4))) float f32x4;

__device__ __forceinline__ float siluf(float v) { return v / (1.f + __expf(-v)); }
__device__ __forceinline__ float softplusf(float v) {
    return (v > 20.f) ? v : log1pf(__expf(v));
}
__device__ __forceinline__ short f2bf(float f) {
    unsigned u = __builtin_bit_cast(unsigned, f);
    unsigned r = (u + 0x7FFFu + ((u >> 16) & 1u)) >> 16;
    return (short)r;
}

// ---------------------------------------------------------------------------
// bf16-MFMA GEMM core over K range [kb,ke): C[m,n] (+)= sum A[m,k]*W[n,k].
// 64x64 tile, 4 waves (2x2). KSTEP=64 sweet spot (R9). Atomic-way scale
// (R13): contention cost ~ ways x locations; 2-way on 1536-wide is benign,
// 12-way on 384-wide is not. kgroup g holds k in [8g,8g+8); thread (m_s,q_s)
// stores groups q_s*GPT..+GPT-1; MFMA reads kg = kh*4+qq.
// AMODE: 1 patch gather, 2 flip-add, 3 LN-fused (gA=stats(mean,rstd))
// SMODE: 0 plain(+bias), 3 patchify store (bias+pos, cls gap), 4 atomicAdd
// ---------------------------------------------------------------------------
template<int AMODE, int SMODE, int KSTEP, int NBUF>
__device__ __forceinline__ void mgemm_core(
    const float* __restrict__ A, int lda,
    const float* __restrict__ W,
    const float* __restrict__ bias,
    float* __restrict__ Cout, int M, int N, int K, int kb, int ke,
    int bm, int bn,
    const float* __restrict__ gA, const float* __restrict__ A2,
    const float* __restrict__ pos,
    short* __restrict__ Ab, short* __restrict__ Wb)
{
    constexpr int GPT = KSTEP / 32;   // kgroups per thread / MFMA rounds
    constexpr int NF4 = KSTEP / 16;   // float4s staged per thread per matrix

    const int tid = threadIdx.x;
    const int m_s = tid >> 2;
    const int q_s = tid & 3;
    const int lane = tid & 63;
    const int wv = tid >> 6;
    const int wm = (wv >> 1) * 32, wn = (wv & 1) * 32;
    const int qq = lane >> 4, lr = lane & 15;

    f32x4 acc[2][2];
    #pragma unroll
    for (int i = 0; i < 2; ++i)
        #pragma unroll
        for (int j = 0; j < 2; ++j)
            acc[i][j] = f32x4{0.f, 0.f, 0.f, 0.f};

    float2 stf = make_float2(0.f, 0.f);
    if (AMODE == 3) {
        int m = bm + m_s;
        if (m < M) stf = ((const float2*)gA)[m];
    }

    float4 pa[NF4], pw[NF4];
    const float4 z4 = make_float4(0.f, 0.f, 0.f, 0.f);

    auto loadA = [&](int k0) {
        int k = k0 + q_s * (KSTEP / 4);
        int m = bm + m_s;
        if (AMODE == 1) {
            int b = m >> 8, t = m & 255;
            int gh = t >> 3, gw = t & 7;
            #pragma unroll
            for (int i = 0; i < NF4; ++i) {
                int ki = k + i * 4;
                int p1 = ki >> 4, p2 = ki & 15;
                pa[i] = *(const float4*)&gA[(size_t)b * 65536 + gh * 2048
                                            + p1 * 128 + gw * 16 + p2];
            }
        } else if (AMODE == 2) {  // flip-add
            if (m < M && k < K) {
                int b = m / LF, l = m - b * LF;
                const float4* s1 = (const float4*)&A[(size_t)m * lda + k];
                const float4* s2 = (const float4*)&A2[(size_t)(b * LF + (LF - 1 - l)) * lda + k];
                #pragma unroll
                for (int i = 0; i < NF4; ++i) {
                    float4 x = s1[i], y = s2[i];
                    pa[i] = make_float4(x.x + y.x, x.y + y.y, x.z + y.z, x.w + y.w);
                }
            } else {
                #pragma unroll
                for (int i = 0; i < NF4; ++i) pa[i] = z4;
            }
        } else {  // AMODE 3: LayerNorm fused during staging
            if (m < M && k < K) {
                const float4* rr = (const float4*)&A[(size_t)m * lda + k];
                const float4* ww = (const float4*)&A2[k];
                const float4* bb = (const float4*)&pos[k];
                #pragma unroll
                for (int i = 0; i < NF4; ++i) {
                    float4 r = rr[i], w = ww[i], b0 = bb[i];
                    pa[i] = make_float4((r.x - stf.x) * stf.y * w.x + b0.x,
                                        (r.y - stf.x) * stf.y * w.y + b0.y,
                                        (r.z - stf.x) * stf.y * w.z + b0.z,
                                        (r.w - stf.x) * stf.y * w.w + b0.w);
                }
            } else {
                #pragma unroll
                for (int i = 0; i < NF4; ++i) pa[i] = z4;
            }
        }
    };
    auto loadW = [&](int k0) {
        int k = k0 + q_s * (KSTEP / 4);
        int n = bn + m_s;
        if (n < N && k < K) {
            const float4* src = (const float4*)&W[(size_t)n * K + k];
            #pragma unroll
            for (int i = 0; i < NF4; ++i) pw[i] = src[i];
        } else {
            #pragma unroll
            for (int i = 0; i < NF4; ++i) pw[i] = z4;
        }
    };
    auto cvt8 = [&](float4 a, float4 b) -> short8 {
        short8 r;
        r[0] = f2bf(a.x); r[1] = f2bf(a.y); r[2] = f2bf(a.z); r[3] = f2bf(a.w);
        r[4] = f2bf(b.x); r[5] = f2bf(b.y); r[6] = f2bf(b.z); r[7] = f2bf(b.w);
        return r;
    };

    loadA(kb);
    loadW(kb);

    int s = 0;
    for (int k0 = kb; k0 < ke; k0 += KSTEP, ++s) {
        const int buf = (NBUF == 2) ? (s & 1) * (KSTEP * 64) : 0;
        #pragma unroll
        for (int g = 0; g < GPT; ++g) {
            *(short8*)&Ab[buf + ((q_s * GPT + g) * 64 + m_s) * 8] = cvt8(pa[2 * g], pa[2 * g + 1]);
            *(short8*)&Wb[buf + ((q_s * GPT + g) * 64 + m_s) * 8] = cvt8(pw[2 * g], pw[2 * g + 1]);
        }
        __syncthreads();
        if (k0 + KSTEP < ke) { loadA(k0 + KSTEP); loadW(k0 + KSTEP); }
        #pragma unroll
        for (int kh = 0; kh < GPT; ++kh) {
            const int kg = kh * 4 + qq;
            short8 af0 = *(const short8*)&Ab[buf + (kg * 64 + wm + lr) * 8];
            short8 af1 = *(const short8*)&Ab[buf + (kg * 64 + wm + 16 + lr) * 8];
            short8 wf0 = *(const short8*)&Wb[buf + (kg * 64 + wn + lr) * 8];
            short8 wf1 = *(const short8*)&Wb[buf + (kg * 64 + wn + 16 + lr) * 8];
            acc[0][0] = __builtin_amdgcn_mfma_f32_16x16x32_bf16(af0, wf0, acc[0][0], 0, 0, 0);
            acc[0][1] = __builtin_amdgcn_mfma_f32_16x16x32_bf16(af0, wf1, acc[0][1], 0, 0, 0);
            acc[1][0] = __builtin_amdgcn_mfma_f32_16x16x32_bf16(af1, wf0, acc[1][0], 0, 0, 0);
            acc[1][1] = __builtin_amdgcn_mfma_f32_16x16x32_bf16(af1, wf1, acc[1][1], 0, 0, 0);
        }
        if (NBUF == 1 && k0 + KSTEP < ke) __syncthreads();
    }

    #pragma unroll
    for (int mi = 0; mi < 2; ++mi) {
        #pragma unroll
        for (int ni = 0; ni < 2; ++ni) {
            int col = bn + wn + ni * 16 + lr;
            if (col >= N) continue;
            #pragma unroll
            for (int r = 0; r < 4; ++r) {
                int row = bm + wm + mi * 16 + qq * 4 + r;
                if (row >= M) continue;
                float v = acc[mi][ni][r];
                if (SMODE == 0) {
                    if (bias) v += bias[col];
                    Cout[(size_t)row * N + col] = v;
                } else if (SMODE == 3) {
                    int b = row >> 8, t = row & 255;
                    int l = (t < POSROW) ? t : t + 1;
                    v += bias[col] + pos[(size_t)l * DMODEL + col];
                    Cout[(size_t)(b * LF + l) * DMODEL + col] = v;
                } else {  // SMODE 4
                    atomicAdd(&Cout[(size_t)row * N + col], v);
                }
            }
        }
    }
}

template<int AMODE, int SMODE, int KSTEP, int NBUF>
__global__ __launch_bounds__(256) void mgemm_k(
    const float* __restrict__ A, int lda,
    const float* __restrict__ W, const float* __restrict__ bias,
    float* __restrict__ Cout, int M, int N, int K, int KS,
    const float* __restrict__ gA, const float* __restrict__ A2,
    const float* __restrict__ pos,
    float* __restrict__ zbuf, int zcount)
{
    __shared__ __align__(16) short Ab[NBUF * KSTEP * 64];
    __shared__ __align__(16) short Wb[NBUF * KSTEP * 64];
    if (zbuf) {
        int nthr = gridDim.x * gridDim.y * 256;
        int gi = (blockIdx.x + blockIdx.y * gridDim.x) * 256 + threadIdx.x;
        for (int i = gi; i < zcount; i += nthr) zbuf[i] = 0.f;
    }
    // XCD-aware bijective swizzle (skipped when nwg % 8 != 0)
    int nwg = gridDim.x * gridDim.y;
    int lin = blockIdx.x + blockIdx.y * gridDim.x;
    if ((nwg & 7) == 0) {
        int ch = nwg >> 3;
        lin = (lin & 7) * ch + (lin >> 3);
    }
    int bx = lin % gridDim.x;
    int by = lin / gridDim.x;
    int ntile = by / KS, ks = by % KS;
    int chunk = K / KS;
    mgemm_core<AMODE, SMODE, KSTEP, NBUF>(A, lda, W, bias, Cout, M, N, K,
                             ks * chunk, ks * chunk + chunk, bx * 64, ntile * 64,
                             gA, A2, pos, Ab, Wb);
}

// ---------------------------------------------------------------------------
// Fused conv(K=4)+SiLU -> xproj MFMA. grid (17 m-tiles, NKC=12 k-chunks, 2 br).
// SINGLE K64 stage per block: one staging burst, one barrier, 8 MFMAs.
// (12-way atomics fine here: XDB=56-wide output scatters contention — R13)
// ---------------------------------------------------------------------------
__global__ __launch_bounds__(256) void xp_k(
    const float* __restrict__ xz,
    const float* __restrict__ cwf, const float* __restrict__ cbf,
    const float* __restrict__ cwb, const float* __restrict__ cbb,
    const float* __restrict__ Wf, const float* __restrict__ Wb,
    float* __restrict__ xcf, float* __restrict__ xcb,
    float* __restrict__ xdbf, float* __restrict__ xdbb)
{
    __shared__ __align__(16) short Ash[4096];
    __shared__ __align__(16) short Wsh[4096];
    const int br = blockIdx.z;
    const int kcid = blockIdx.y;           // 0..NKC-1, 64-wide d-chunk
    const float* cw = br ? cwb : cwf;
    const float* cbv = br ? cbb : cbf;
    const float* W  = br ? Wb  : Wf;
    float* xco      = br ? xcb : xcf;
    float* xdo      = br ? xdbb : xdbf;

    const int tid = threadIdx.x;
    const int m_s = tid >> 2, q_s = tid & 3;
    const int bm = blockIdx.x * 64;
    const int kb = kcid * 64;
    const int lane = tid & 63, wv = tid >> 6;
    const int wm = (wv >> 1) * 32, wn = (wv & 1) * 32;
    const int qq = lane >> 4, lr = lane & 15;
    const int m = bm + m_s;
    const bool mok = (m < MR);
    int b = 0, l = 0;
    if (mok) { b = m / LF; l = m - b * LF; }

    // ---- conv+SiLU for 16 d-values [d0, d0+16) ----
    const int d0 = kb + q_s * 16;
    float a16[16];
    if (mok) {
        #pragma unroll
        for (int i = 0; i < 4; ++i) {
            float4 c = ((const float4*)&cbv[d0])[i];
            a16[4 * i] = c.x; a16[4 * i + 1] = c.y;
            a16[4 * i + 2] = c.z; a16[4 * i + 3] = c.w;
        }
        float wreg[16][4];
        #pragma unroll
        for (int j = 0; j < 16; ++j)
            *(float4*)wreg[j] = *(const float4*)&cw[(d0 + j) * 4];
        #pragma unroll
        for (int kk = 0; kk < 4; ++kk) {
            int li = l - 3 + kk;
            if (li >= 0) {
                int srow = br ? (b * LF + (LF - 1 - li)) : (b * LF + li);
                const float4* xp = (const float4*)&xz[(size_t)srow * 2 * DIN + d0];
                #pragma unroll
                for (int i = 0; i < 4; ++i) {
                    float4 x = xp[i];
                    a16[4 * i]     += x.x * wreg[4 * i][kk];
                    a16[4 * i + 1] += x.y * wreg[4 * i + 1][kk];
                    a16[4 * i + 2] += x.z * wreg[4 * i + 2][kk];
                    a16[4 * i + 3] += x.w * wreg[4 * i + 3][kk];
                }
            }
        }
        #pragma unroll
        for (int j = 0; j < 16; ++j) a16[j] = siluf(a16[j]);
    } else {
        #pragma unroll
        for (int j = 0; j < 16; ++j) a16[j] = 0.f;
    }

    // ---- W fragment (16 k-values for row m_s) ----
    float4 pw[4];
    {
        const float4 z4 = make_float4(0.f, 0.f, 0.f, 0.f);
        if (m_s < XDB) {
            const float4* src = (const float4*)&W[(size_t)m_s * DIN + kb + q_s * 16];
            pw[0] = src[0]; pw[1] = src[1]; pw[2] = src[2]; pw[3] = src[3];
        } else { pw[0] = z4; pw[1] = z4; pw[2] = z4; pw[3] = z4; }
    }

    auto cvt8a = [&](int o) -> short8 {
        short8 r;
        #pragma unroll
        for (int j = 0; j < 8; ++j) r[j] = f2bf(a16[o + j]);
        return r;
    };
    auto cvt8w = [&](float4 a, float4 b) -> short8 {
        short8 r;
        r[0] = f2bf(a.x); r[1] = f2bf(a.y); r[2] = f2bf(a.z); r[3] = f2bf(a.w);
        r[4] = f2bf(b.x); r[5] = f2bf(b.y); r[6] = f2bf(b.z); r[7] = f2bf(b.w);
        return r;
    };

    *(short8*)&Ash[((2 * q_s) * 64 + m_s) * 8]     = cvt8a(0);
    *(short8*)&Ash[((2 * q_s + 1) * 64 + m_s) * 8] = cvt8a(8);
    *(short8*)&Wsh[((2 * q_s) * 64 + m_s) * 8]     = cvt8w(pw[0], pw[1]);
    *(short8*)&Wsh[((2 * q_s + 1) * 64 + m_s) * 8] = cvt8w(pw[2], pw[3]);
    if (mok) {  // side-product: materialize xc for the scan kernels
        float4* dst = (float4*)&xco[(size_t)m * DIN + d0];
        dst[0] = make_float4(a16[0], a16[1], a16[2], a16[3]);
        dst[1] = make_float4(a16[4], a16[5], a16[6], a16[7]);
        dst[2] = make_float4(a16[8], a16[9], a16[10], a16[11]);
        dst[3] = make_float4(a16[12], a16[13], a16[14], a16[15]);
    }
    __syncthreads();

    f32x4 acc[2][2];
    #pragma unroll
    for (int i = 0; i < 2; ++i)
        #pragma unroll
        for (int j = 0; j < 2; ++j)
            acc[i][j] = f32x4{0.f, 0.f, 0.f, 0.f};

    #pragma unroll
    for (int kh = 0; kh < 2; ++kh) {
        const int kg = kh * 4 + qq;
        short8 af0 = *(const short8*)&Ash[(kg * 64 + wm + lr) * 8];
        short8 af1 = *(const short8*)&Ash[(kg * 64 + wm + 16 + lr) * 8];
        short8 wf0 = *(const short8*)&Wsh[(kg * 64 + wn + lr) * 8];
        short8 wf1 = *(const short8*)&Wsh[(kg * 64 + wn + 16 + lr) * 8];
        acc[0][0] = __builtin_amdgcn_mfma_f32_16x16x32_bf16(af0, wf0, acc[0][0], 0, 0, 0);
        acc[0][1] = __builtin_amdgcn_mfma_f32_16x16x32_bf16(af0, wf1, acc[0][1], 0, 0, 0);
        acc[1][0] = __builtin_amdgcn_mfma_f32_16x16x32_bf16(af1, wf0, acc[1][0], 0, 0, 0);
        acc[1][1] = __builtin_amdgcn_mfma_f32_16x16x32_bf16(af1, wf1, acc[1][1], 0, 0, 0);
    }

    #pragma unroll
    for (int mi = 0; mi < 2; ++mi) {
        #pragma unroll
        for (int ni = 0; ni < 2; ++ni) {
            int col = wn + ni * 16 + lr;
            if (col >= XDB) continue;
            #pragma unroll
            for (int r = 0; r < 4; ++r) {
                int row = bm + wm + mi * 16 + qq * 4 + r;
                if (row >= MR) continue;
                atomicAdd(&xdo[(size_t)row * XDB + col], acc[mi][ni][r]);
            }
        }
    }
}

// cls row: residual[b, 128, :] = cls + pos[128]
__global__ void cls_k(const float* __restrict__ cls, const float* __restrict__ pos,
                      float* __restrict__ residual) {
    int b = blockIdx.x, t = threadIdx.x;
    residual[(size_t)(b * LF + POSROW) * DMODEL + t] =
        cls[t] + pos[(size_t)POSROW * DMODEL + t];
}

// row-wise layernorm STATS over 384 -> (mean, rstd) per row.
// Also zeroes this row of xz (2*DIN floats) for in_proj's split-K atomics.
__global__ __launch_bounds__(128) void lnstat_k(const float* __restrict__ X,
                                                float2* __restrict__ st,
                                                float* __restrict__ xz_zero) {
    int r = blockIdx.x;
    const float* x = X + (size_t)r * DMODEL;
    int t = threadIdx.x;
    // zero xz row r: 2*DIN = 1536 floats = 384 float4s, 3 per thread
    {
        float4* zrow = (float4*)&xz_zero[(size_t)r * 2 * DIN];
        const float4 z4 = make_float4(0.f, 0.f, 0.f, 0.f);
        #pragma unroll
        for (int i = 0; i < 3; ++i) zrow[t + i * 128] = z4;
    }
    float v0 = x[t], v1 = x[t + 128], v2 = x[t + 256];
    float s = v0 + v1 + v2;
    float sq = v0 * v0 + v1 * v1 + v2 * v2;
    #pragma unroll
    for (int o = 32; o > 0; o >>= 1) {
        s += __shfl_down(s, o);
        sq += __shfl_down(sq, o);
    }
    __shared__ float ls[2], lq[2];
    if ((t & 63) == 0) { ls[t >> 6] = s; lq[t >> 6] = sq; }
    __syncthreads();
    if (t == 0) {
        float S = ls[0] + ls[1], Q = lq[0] + lq[1];
        float mean = S * (1.f / 384.f);
        float var = Q * (1.f / 384.f) - mean * mean;
        st[r] = make_float2(mean, rsqrtf(var + 1e-5f));
    }
}

// ---------------------------------------------------------------------------
// Chunked scan (CL=16), SPLIT-NST: 2 paired lanes per d-column, 8 states each.
// scanA materializes dt; scanC consumes it (dt-handoff) and prefix-combines
// with the suffix-sum trick (serial chain = 1 add per chunk).
// ---------------------------------------------------------------------------
__global__ __launch_bounds__(256) void scanA_k(
    const float* __restrict__ xcf, const float* __restrict__ xcb,
    const float* __restrict__ xdbf, const float* __restrict__ xdbb,
    const float* __restrict__ alf, const float* __restrict__ alb,
    const float* __restrict__ dwf, const float* __restrict__ dbf,
    const float* __restrict__ dwb, const float* __restrict__ dbb,
    float* __restrict__ hpart, float* __restrict__ sumd,
    float* __restrict__ dtf, float* __restrict__ dtb) {
    const int t = threadIdx.x;
    const int half = t & 1, dl = t >> 1;
    const int y = blockIdx.y;            // b*2+br
    const int b = y >> 1, br = y & 1;
    const int c = blockIdx.z;
    const int d = blockIdx.x * 128 + dl;
    const float* xc  = br ? xcb  : xcf;
    const float* xdb = br ? xdbb : xdbf;
    const float* Al  = br ? alb  : alf;
    const float* dw  = br ? dwb  : dwf;
    const float* dbi = br ? dbb  : dbf;
    float* dto       = br ? dtb  : dtf;

    float An[8];
    #pragma unroll
    for (int n = 0; n < 8; ++n)
        An[n] = -__expf(Al[(size_t)d * NST + half * 8 + n]);
    float wdt[DTR];
    #pragma unroll
    for (int k = 0; k < DTR; k += 4)
        *(float4*)&wdt[k] = *(const float4*)&dw[(size_t)d * DTR + k];
    float dbv = dbi[d];

    // batch-prefetch xc values for all CL steps (independent loads)
    float xr[CL];
    #pragma unroll
    for (int s = 0; s < CL; ++s) {
        int l = c * CL + s;
        xr[s] = (l < LF) ? xc[(size_t)(b * LF + l) * DIN + d] : 0.f;
    }

    __shared__ float sXD[CL][DTR];
    __shared__ float sB[CL][NST];
    for (int idx = t; idx < CL * DTR; idx += 256) {
        int s0 = idx / DTR, j0 = idx - s0 * DTR;
        int l0 = c * CL + s0;
        sXD[s0][j0] = (l0 < LF) ? xdb[(size_t)(b * LF + l0) * XDB + j0] : 0.f;
    }
    {
        int s0 = t >> 4, j0 = t & 15;
        int l0 = c * CL + s0;
        sB[s0][j0] = (l0 < LF) ? xdb[(size_t)(b * LF + l0) * XDB + DTR + j0] : 0.f;
    }
    __syncthreads();

    float h[8] = {};
    float sdt = 0.f;
    #pragma unroll
    for (int s = 0; s < CL; ++s) {
        int l = c * CL + s;
        if (l < LF) {
            float dtv = dbv;
            #pragma unroll
            for (int k = 0; k < DTR; ++k) dtv += sXD[s][k] * wdt[k];
            dtv = softplusf(dtv);
            if (half == 0) dto[(size_t)(b * LF + l) * DIN + d] = dtv;
            sdt += dtv;
            float dtx = dtv * xr[s];
            #pragma unroll
            for (int n = 0; n < 8; ++n)
                h[n] = __expf(dtv * An[n]) * h[n] + dtx * sB[s][half * 8 + n];
        }
    }
    size_t base = (size_t)(c * 8 + y) * NST;
    #pragma unroll
    for (int n = 0; n < 8; ++n)
        hpart[(base + half * 8 + n) * DIN + d] = h[n];
    if (half == 0) sumd[(size_t)(c * 8 + y) * DIN + d] = sdt;
}

__global__ __launch_bounds__(256) void scanC_k(
    const float* __restrict__ xcf, const float* __restrict__ xcb,
    const float* __restrict__ xdbf, const float* __restrict__ xdbb,
    const float* __restrict__ xz,
    const float* __restrict__ alf, const float* __restrict__ dpf,
    const float* __restrict__ alb, const float* __restrict__ dpb,
    const float* __restrict__ dtf, const float* __restrict__ dtb,
    const float* __restrict__ hpart, const float* __restrict__ sumd,
    float* __restrict__ yf, float* __restrict__ yb) {
    const int t = threadIdx.x;
    const int half = t & 1, dl = t >> 1;
    const int y = blockIdx.y;
    const int b = y >> 1, br = y & 1;
    const int c = blockIdx.z;
    const int d = blockIdx.x * 128 + dl;
    const float* xc  = br ? xcb  : xcf;
    const float* xdb = br ? xdbb : xdbf;
    const float* Al  = br ? alb  : alf;
    const float* Dpp = br ? dpb  : dpf;
    const float* dti = br ? dtb  : dtf;
    float* yo        = br ? yb   : yf;

    float An[8];
    #pragma unroll
    for (int n = 0; n < 8; ++n)
        An[n] = -__expf(Al[(size_t)d * NST + half * 8 + n]);
    float Dv = Dpp[d];

    // batch-prefetch dt, xc and z values for all CL steps (independent loads)
    float dtr[CL], xr[CL], zr[CL];
    #pragma unroll
    for (int s = 0; s < CL; ++s) {
        int l = c * CL + s;
        if (l < LF) {
            size_t rowoff = (size_t)(b * LF + l) * DIN + d;
            dtr[s] = dti[rowoff];
            xr[s] = xc[rowoff];
            int zl = br ? (LF - 1 - l) : l;
            zr[s] = xz[(size_t)(b * LF + zl) * (2 * DIN) + DIN + d];
        } else { dtr[s] = 0.f; xr[s] = 0.f; zr[s] = 0.f; }
    }

    __shared__ float sB[CL][NST];
    __shared__ float sC[CL][NST];
    {
        int s0 = t >> 4, j0 = t & 15;
        int l0 = c * CL + s0;
        size_t rb = (size_t)(b * LF + l0) * XDB + DTR;
        sB[s0][j0] = (l0 < LF) ? xdb[rb + j0] : 0.f;
        sC[s0][j0] = (l0 < LF) ? xdb[rb + NST + j0] : 0.f;
    }
    __syncthreads();

    // prefix-combine earlier chunks, DESCENDING with running suffix-sum:
    // h[n] = sum_j exp(An*S_j)*hp_j[n], S_j = sum_{j'>j} sd_{j'}.
    // Serial chain is one add per j; loads/exps are independent.
    float h[8] = {};
    float suf = 0.f;
    for (int j = c - 1; j >= 0; --j) {
        float sd = sumd[(size_t)(j * 8 + y) * DIN + d];
        size_t bj = (size_t)(j * 8 + y) * NST;
        #pragma unroll
        for (int n = 0; n < 8; ++n)
            h[n] += __expf(An[n] * suf) * hpart[(bj + half * 8 + n) * DIN + d];
        suf += sd;
    }

    #pragma unroll
    for (int s = 0; s < CL; ++s) {
        int l = c * CL + s;
        if (l < LF) {
            int row = b * LF + l;
            float dtv = dtr[s];
            float dtx = dtv * xr[s];
            float acc = 0.f;
            #pragma unroll
            for (int n = 0; n < 8; ++n) {
                h[n] = __expf(dtv * An[n]) * h[n] + dtx * sB[s][half * 8 + n];
                acc += h[n] * sC[s][half * 8 + n];
            }
            acc += __shfl_xor(acc, 1);   // combine the two halves' partial sums
            if (half == 0)
                yo[(size_t)row * DIN + d] = (acc + xr[s] * Dv) * siluf(zr[s]);
        }
    }
}

// final LN(row POS) + command MLP + add -> f32 out
__global__ __launch_bounds__(384) void final_k(
    const float* __restrict__ residual,
    const float* __restrict__ lnw, const float* __restrict__ lnb,
    const float* __restrict__ sv, const float* __restrict__ act,
    const float* __restrict__ cw1, const float* __restrict__ cb1,
    const float* __restrict__ cw2, const float* __restrict__ cb2,
    float* __restrict__ out) {
    int b = blockIdx.x, t = threadIdx.x;
    const float* x = residual + (size_t)(b * LF + POSROW) * DMODEL;
    float v = x[t];
    float s = v, sq = v * v;
    #pragma unroll
    for (int o = 32; o > 0; o >>= 1) {
        s += __shfl_down(s, o);
        sq += __shfl_down(sq, o);
    }
    __shared__ float ls[6], lq[6], hid[DMODEL], cmdin[20];
    if ((t & 63) == 0) { ls[t >> 6] = s; lq[t >> 6] = sq; }
    if (t < 20) cmdin[t] = (t < 16) ? sv[b * 16 + t] : act[b * 4 + t - 16];
    __syncthreads();
    float S = 0.f, Q = 0.f;
    #pragma unroll
    for (int w = 0; w < 6; ++w) { S += ls[w]; Q += lq[w]; }
    float mean = S * (1.f / 384.f);
    float var = Q * (1.f / 384.f) - mean * mean;
    float rs = rsqrtf(var + 1e-5f);
    float vis = (v - mean) * rs * lnw[t] + lnb[t];
    float a1 = cb1[t];
    #pragma unroll
    for (int k = 0; k < 20; ++k) a1 += cmdin[k] * cw1[t * 20 + k];
    hid[t] = fmaxf(a1, 0.f);
    __syncthreads();
    float a2 = cb2[t];
    for (int k = 0; k < DMODEL; ++k) a2 += hid[k] * cw2[t * DMODEL + k];
    out[b * DMODEL + t] = vis + a2;
}

extern "C" void kernel_launch(void* const* d_in, const int* in_sizes, int n_in,
                              void* d_out, int out_size, void* d_ws, size_t ws_size,
                              hipStream_t stream) {
    const float* depth_seq = (const float*)d_in[0];
    const float* state_vec = (const float*)d_in[1];
    const float* action    = (const float*)d_in[2];
    const float* patch_w   = (const float*)d_in[3];
    const float* patch_b   = (const float*)d_in[4];
    const float* cls_token = (const float*)d_in[5];
    const float* pos_embed = (const float*)d_in[6];
    const float* ln_w      = (const float*)d_in[7];
    const float* ln_b      = (const float*)d_in[8];
    const float* in_proj_w = (const float*)d_in[9];
    const float* conv_w    = (const float*)d_in[10];
    const float* conv_b    = (const float*)d_in[11];
    const float* conv_wb   = (const float*)d_in[12];
    const float* conv_bb   = (const float*)d_in[13];
    const float* xproj_w   = (const float*)d_in[14];
    const float* xproj_wb  = (const float*)d_in[15];
    const float* dtproj_w  = (const float*)d_in[16];
    const float* dtproj_b  = (const float*)d_in[17];
    const float* dtproj_wb = (const float*)d_in[18];
    const float* dtproj_bb = (const float*)d_in[19];
    const float* A_log     = (const float*)d_in[20];
    const float* A_logb    = (const float*)d_in[21];
    const float* Dp        = (const float*)d_in[22];
    const float* Dpb       = (const float*)d_in[23];
    const float* out_w     = (const float*)d_in[24];
    const float* lnf_w     = (const float*)d_in[25];
    const float* lnf_b     = (const float*)d_in[26];
    const float* cw1       = (const float*)d_in[27];
    const float* cb1       = (const float*)d_in[28];
    const float* cw2       = (const float*)d_in[29];
    const float* cb2       = (const float*)d_in[30];

    float* ws = (float*)d_ws;
    size_t o = 0;
    float* residual = ws + o; o += (size_t)MR * DMODEL;
    float* xz       = ws + o; o += (size_t)MR * 2 * DIN;
    float* xcf      = ws + o; o += (size_t)MR * DIN;
    float* xcb      = ws + o; o += (size_t)MR * DIN;
    float* xdbf     = ws + o; o += (size_t)MR * XDB;   // adjacent pair:
    float* xdbb     = ws + o; o += (size_t)MR * XDB;   // zeroed by in_proj
    float* yfb      = ws + o; o += (size_t)MR * DIN;
    float* ybb      = ws + o; o += (size_t)MR * DIN;
    float* hpart    = ws + o; o += (size_t)NC * 8 * NST * DIN;
    float* sumd     = ws + o; o += (size_t)NC * 8 * DIN;
    float* dtf      = ws + o; o += (size_t)MR * DIN;   // dt handoff (fwd)
    float* dtb      = ws + o; o += (size_t)MR * DIN;   // dt handoff (bwd)
    float2* stats   = (float2*)(ws + o); o += (size_t)MR * 2;
    (void)ws_size; (void)in_sizes; (void)n_in; (void)out_size;

    // patchify -> residual (bias + pos, cls gap), MFMA, K64 x 4 steps
    mgemm_k<1, 3, 64, 2><<<dim3(16, 6), 256, 0, stream>>>(
        nullptr, 0, patch_w, patch_b, residual, 1024, DMODEL, 256, 1,
        depth_seq, nullptr, pos_embed, nullptr, 0);
    cls_k<<<BB, DMODEL, 0, stream>>>(cls_token, pos_embed, residual);

    for (int i = 0; i < 4; ++i) {
        // LN stats (one pass per layer) + zero xz for in_proj's atomics
        lnstat_k<<<MR, 128, 0, stream>>>(residual, stats, xz);
        // in_proj with fused LN, SPLIT-K 2 (K64 x 3 steps each, 816 blocks,
        // 2-way atomics over 1536-wide f32 output); also zeroes xdb for xp_k
        mgemm_k<3, 4, 64, 2><<<dim3(17, 24 * 2), 256, 0, stream>>>(
            residual, DMODEL, in_proj_w + (size_t)i * 2 * DIN * DMODEL, nullptr,
            xz, MR, 2 * DIN, DMODEL, 2,
            (const float*)stats, ln_w + (size_t)i * DMODEL, ln_b + (size_t)i * DMODEL,
            xdbf, 2 * MR * XDB);
        // fused conv+SiLU + xproj (single K64 stage per block, NKC=12)
        xp_k<<<dim3(17, NKC, 2), 256, 0, stream>>>(
            xz, conv_w + (size_t)i * DIN * 4, conv_b + (size_t)i * DIN,
            conv_wb + (size_t)i * DIN * 4, conv_bb + (size_t)i * DIN,
            xproj_w + (size_t)i * XDB * DIN, xproj_wb + (size_t)i * XDB * DIN,
            xcf, xcb, xdbf, xdbb);
        // chunked scan (CL=16): scanA materializes dt, scanC consumes it
        scanA_k<<<dim3(6, 8, NC), 256, 0, stream>>>(
            xcf, xcb, xdbf, xdbb,
            A_log + (size_t)i * DIN * NST, A_logb + (size_t)i * DIN * NST,
            dtproj_w + (size_t)i * DIN * DTR, dtproj_b + (size_t)i * DIN,
            dtproj_wb + (size_t)i * DIN * DTR, dtproj_bb + (size_t)i * DIN,
            hpart, sumd, dtf, dtb);
        scanC_k<<<dim3(6, 8, NC), 256, 0, stream>>>(
            xcf, xcb, xdbf, xdbb, xz,
            A_log + (size_t)i * DIN * NST, Dp + (size_t)i * DIN,
            A_logb + (size_t)i * DIN * NST, Dpb + (size_t)i * DIN,
            dtf, dtb, hpart, sumd, yfb, ybb);
        // out_proj flip-add, split-K 4, K64 x 3 steps (dbuf), atomicAdd
        mgemm_k<2, 4, 64, 2><<<dim3(17, 6 * 4), 256, 0, stream>>>(
            yfb, DIN, out_w + (size_t)i * DMODEL * DIN, nullptr,
            residual, MR, DMODEL, DIN, 4, nullptr, ybb, nullptr, nullptr, 0);
    }

    final_k<<<BB, DMODEL, 0, stream>>>(
        residual, lnf_w, lnf_b, state_vec, action, cw1, cb1, cw2, cb2,
        (float*)d_out);
}

// Round 16
// 494.291 us; speedup vs baseline: 1.0476x; 1.0476x over previous
//
#include <hip/hip_runtime.h>
#include <hip/hip_bf16.h>
#include <math.h>

#define BB 4
#define LF 257      // NTOK+1
#define MR 1028     // BB*LF
#define DMODEL 384
#define DIN 768
#define NST 16
#define DTR 24
#define XDB 56      // DTR + 2*N
#define POSROW 128
#define CL 16       // scan chunk length (R12 lesson: CL=8 doubles hpart traffic)
#define NC 17       // ceil(LF/CL)
#define NKC 12      // xp_k split-K chunks (64 wide, single K64 stage each)

typedef __attribute__((ext_vector_type(8))) short short8;
typedef __attribute__((ext_vector_type(4))) float f32x4;

__device__ __forceinline__ float siluf(float v) { return v / (1.f + __expf(-v)); }
__device__ __forceinline__ float softplusf(float v) {
    return (v > 20.f) ? v : log1pf(__expf(v));
}
__device__ __forceinline__ short f2bf(float f) {
    unsigned u = __builtin_bit_cast(unsigned, f);
    unsigned r = (u + 0x7FFFu + ((u >> 16) & 1u)) >> 16;
    return (short)r;
}

// ---------------------------------------------------------------------------
// bf16-MFMA GEMM core over K range [kb,ke): C[m,n] (+)= sum A[m,k]*W[n,k].
// 64x64 tile, 4 waves (2x2). KSTEP=64 sweet spot (R9). Atomic-cost model
// (R13/R15): cost ~ total atomic ops; only narrow outputs amortize split-K
// single-stage (xp_k 56-wide OK; 384/1536-wide f32 outputs do not).
// kgroup g holds k in [8g,8g+8); thread (m_s,q_s) stores groups
// q_s*GPT..+GPT-1; MFMA reads kg = kh*4+qq.
// AMODE: 1 patch gather, 2 flip-add, 3 LN-fused (gA=stats(mean,rstd))
// SMODE: 0 plain(+bias), 3 patchify store (bias+pos, cls gap), 4 atomicAdd
// ---------------------------------------------------------------------------
template<int AMODE, int SMODE, int KSTEP, int NBUF>
__device__ __forceinline__ void mgemm_core(
    const float* __restrict__ A, int lda,
    const float* __restrict__ W,
    const float* __restrict__ bias,
    float* __restrict__ Cout, int M, int N, int K, int kb, int ke,
    int bm, int bn,
    const float* __restrict__ gA, const float* __restrict__ A2,
    const float* __restrict__ pos,
    short* __restrict__ Ab, short* __restrict__ Wb)
{
    constexpr int GPT = KSTEP / 32;   // kgroups per thread / MFMA rounds
    constexpr int NF4 = KSTEP / 16;   // float4s staged per thread per matrix

    const int tid = threadIdx.x;
    const int m_s = tid >> 2;
    const int q_s = tid & 3;
    const int lane = tid & 63;
    const int wv = tid >> 6;
    const int wm = (wv >> 1) * 32, wn = (wv & 1) * 32;
    const int qq = lane >> 4, lr = lane & 15;

    f32x4 acc[2][2];
    #pragma unroll
    for (int i = 0; i < 2; ++i)
        #pragma unroll
        for (int j = 0; j < 2; ++j)
            acc[i][j] = f32x4{0.f, 0.f, 0.f, 0.f};

    float2 stf = make_float2(0.f, 0.f);
    if (AMODE == 3) {
        int m = bm + m_s;
        if (m < M) stf = ((const float2*)gA)[m];
    }

    float4 pa[NF4], pw[NF4];
    const float4 z4 = make_float4(0.f, 0.f, 0.f, 0.f);

    auto loadA = [&](int k0) {
        int k = k0 + q_s * (KSTEP / 4);
        int m = bm + m_s;
        if (AMODE == 1) {
            int b = m >> 8, t = m & 255;
            int gh = t >> 3, gw = t & 7;
            #pragma unroll
            for (int i = 0; i < NF4; ++i) {
                int ki = k + i * 4;
                int p1 = ki >> 4, p2 = ki & 15;
                pa[i] = *(const float4*)&gA[(size_t)b * 65536 + gh * 2048
                                            + p1 * 128 + gw * 16 + p2];
            }
        } else if (AMODE == 2) {  // flip-add
            if (m < M && k < K) {
                int b = m / LF, l = m - b * LF;
                const float4* s1 = (const float4*)&A[(size_t)m * lda + k];
                const float4* s2 = (const float4*)&A2[(size_t)(b * LF + (LF - 1 - l)) * lda + k];
                #pragma unroll
                for (int i = 0; i < NF4; ++i) {
                    float4 x = s1[i], y = s2[i];
                    pa[i] = make_float4(x.x + y.x, x.y + y.y, x.z + y.z, x.w + y.w);
                }
            } else {
                #pragma unroll
                for (int i = 0; i < NF4; ++i) pa[i] = z4;
            }
        } else {  // AMODE 3: LayerNorm fused during staging
            if (m < M && k < K) {
                const float4* rr = (const float4*)&A[(size_t)m * lda + k];
                const float4* ww = (const float4*)&A2[k];
                const float4* bb = (const float4*)&pos[k];
                #pragma unroll
                for (int i = 0; i < NF4; ++i) {
                    float4 r = rr[i], w = ww[i], b0 = bb[i];
                    pa[i] = make_float4((r.x - stf.x) * stf.y * w.x + b0.x,
                                        (r.y - stf.x) * stf.y * w.y + b0.y,
                                        (r.z - stf.x) * stf.y * w.z + b0.z,
                                        (r.w - stf.x) * stf.y * w.w + b0.w);
                }
            } else {
                #pragma unroll
                for (int i = 0; i < NF4; ++i) pa[i] = z4;
            }
        }
    };
    auto loadW = [&](int k0) {
        int k = k0 + q_s * (KSTEP / 4);
        int n = bn + m_s;
        if (n < N && k < K) {
            const float4* src = (const float4*)&W[(size_t)n * K + k];
            #pragma unroll
            for (int i = 0; i < NF4; ++i) pw[i] = src[i];
        } else {
            #pragma unroll
            for (int i = 0; i < NF4; ++i) pw[i] = z4;
        }
    };
    auto cvt8 = [&](float4 a, float4 b) -> short8 {
        short8 r;
        r[0] = f2bf(a.x); r[1] = f2bf(a.y); r[2] = f2bf(a.z); r[3] = f2bf(a.w);
        r[4] = f2bf(b.x); r[5] = f2bf(b.y); r[6] = f2bf(b.z); r[7] = f2bf(b.w);
        return r;
    };

    loadA(kb);
    loadW(kb);

    int s = 0;
    for (int k0 = kb; k0 < ke; k0 += KSTEP, ++s) {
        const int buf = (NBUF == 2) ? (s & 1) * (KSTEP * 64) : 0;
        #pragma unroll
        for (int g = 0; g < GPT; ++g) {
            *(short8*)&Ab[buf + ((q_s * GPT + g) * 64 + m_s) * 8] = cvt8(pa[2 * g], pa[2 * g + 1]);
            *(short8*)&Wb[buf + ((q_s * GPT + g) * 64 + m_s) * 8] = cvt8(pw[2 * g], pw[2 * g + 1]);
        }
        __syncthreads();
        if (k0 + KSTEP < ke) { loadA(k0 + KSTEP); loadW(k0 + KSTEP); }
        #pragma unroll
        for (int kh = 0; kh < GPT; ++kh) {
            const int kg = kh * 4 + qq;
            short8 af0 = *(const short8*)&Ab[buf + (kg * 64 + wm + lr) * 8];
            short8 af1 = *(const short8*)&Ab[buf + (kg * 64 + wm + 16 + lr) * 8];
            short8 wf0 = *(const short8*)&Wb[buf + (kg * 64 + wn + lr) * 8];
            short8 wf1 = *(const short8*)&Wb[buf + (kg * 64 + wn + 16 + lr) * 8];
            acc[0][0] = __builtin_amdgcn_mfma_f32_16x16x32_bf16(af0, wf0, acc[0][0], 0, 0, 0);
            acc[0][1] = __builtin_amdgcn_mfma_f32_16x16x32_bf16(af0, wf1, acc[0][1], 0, 0, 0);
            acc[1][0] = __builtin_amdgcn_mfma_f32_16x16x32_bf16(af1, wf0, acc[1][0], 0, 0, 0);
            acc[1][1] = __builtin_amdgcn_mfma_f32_16x16x32_bf16(af1, wf1, acc[1][1], 0, 0, 0);
        }
        if (NBUF == 1 && k0 + KSTEP < ke) __syncthreads();
    }

    #pragma unroll
    for (int mi = 0; mi < 2; ++mi) {
        #pragma unroll
        for (int ni = 0; ni < 2; ++ni) {
            int col = bn + wn + ni * 16 + lr;
            if (col >= N) continue;
            #pragma unroll
            for (int r = 0; r < 4; ++r) {
                int row = bm + wm + mi * 16 + qq * 4 + r;
                if (row >= M) continue;
                float v = acc[mi][ni][r];
                if (SMODE == 0) {
                    if (bias) v += bias[col];
                    Cout[(size_t)row * N + col] = v;
                } else if (SMODE == 3) {
                    int b = row >> 8, t = row & 255;
                    int l = (t < POSROW) ? t : t + 1;
                    v += bias[col] + pos[(size_t)l * DMODEL + col];
                    Cout[(size_t)(b * LF + l) * DMODEL + col] = v;
                } else {  // SMODE 4
                    atomicAdd(&Cout[(size_t)row * N + col], v);
                }
            }
        }
    }
}

template<int AMODE, int SMODE, int KSTEP, int NBUF>
__global__ __launch_bounds__(256) void mgemm_k(
    const float* __restrict__ A, int lda,
    const float* __restrict__ W, const float* __restrict__ bias,
    float* __restrict__ Cout, int M, int N, int K, int KS,
    const float* __restrict__ gA, const float* __restrict__ A2,
    const float* __restrict__ pos,
    float* __restrict__ zbuf, int zcount)
{
    __shared__ __align__(16) short Ab[NBUF * KSTEP * 64];
    __shared__ __align__(16) short Wb[NBUF * KSTEP * 64];
    if (zbuf) {
        int nthr = gridDim.x * gridDim.y * 256;
        int gi = (blockIdx.x + blockIdx.y * gridDim.x) * 256 + threadIdx.x;
        for (int i = gi; i < zcount; i += nthr) zbuf[i] = 0.f;
    }
    // XCD-aware bijective swizzle (skipped when nwg % 8 != 0)
    int nwg = gridDim.x * gridDim.y;
    int lin = blockIdx.x + blockIdx.y * gridDim.x;
    if ((nwg & 7) == 0) {
        int ch = nwg >> 3;
        lin = (lin & 7) * ch + (lin >> 3);
    }
    int bx = lin % gridDim.x;
    int by = lin / gridDim.x;
    int ntile = by / KS, ks = by % KS;
    int chunk = K / KS;
    mgemm_core<AMODE, SMODE, KSTEP, NBUF>(A, lda, W, bias, Cout, M, N, K,
                             ks * chunk, ks * chunk + chunk, bx * 64, ntile * 64,
                             gA, A2, pos, Ab, Wb);
}

// ---------------------------------------------------------------------------
// Fused conv(K=4)+SiLU -> xproj MFMA. grid (17 m-tiles, NKC=12 k-chunks, 2 br).
// SINGLE K64 stage per block: one staging burst, one barrier, 8 MFMAs.
// (12-way atomics fine here: XDB=56-wide output scatters contention — R13)
// ---------------------------------------------------------------------------
__global__ __launch_bounds__(256) void xp_k(
    const float* __restrict__ xz,
    const float* __restrict__ cwf, const float* __restrict__ cbf,
    const float* __restrict__ cwb, const float* __restrict__ cbb,
    const float* __restrict__ Wf, const float* __restrict__ Wb,
    float* __restrict__ xcf, float* __restrict__ xcb,
    float* __restrict__ xdbf, float* __restrict__ xdbb)
{
    __shared__ __align__(16) short Ash[4096];
    __shared__ __align__(16) short Wsh[4096];
    const int br = blockIdx.z;
    const int kcid = blockIdx.y;           // 0..NKC-1, 64-wide d-chunk
    const float* cw = br ? cwb : cwf;
    const float* cbv = br ? cbb : cbf;
    const float* W  = br ? Wb  : Wf;
    float* xco      = br ? xcb : xcf;
    float* xdo      = br ? xdbb : xdbf;

    const int tid = threadIdx.x;
    const int m_s = tid >> 2, q_s = tid & 3;
    const int bm = blockIdx.x * 64;
    const int kb = kcid * 64;
    const int lane = tid & 63, wv = tid >> 6;
    const int wm = (wv >> 1) * 32, wn = (wv & 1) * 32;
    const int qq = lane >> 4, lr = lane & 15;
    const int m = bm + m_s;
    const bool mok = (m < MR);
    int b = 0, l = 0;
    if (mok) { b = m / LF; l = m - b * LF; }

    // ---- conv+SiLU for 16 d-values [d0, d0+16) ----
    const int d0 = kb + q_s * 16;
    float a16[16];
    if (mok) {
        #pragma unroll
        for (int i = 0; i < 4; ++i) {
            float4 c = ((const float4*)&cbv[d0])[i];
            a16[4 * i] = c.x; a16[4 * i + 1] = c.y;
            a16[4 * i + 2] = c.z; a16[4 * i + 3] = c.w;
        }
        float wreg[16][4];
        #pragma unroll
        for (int j = 0; j < 16; ++j)
            *(float4*)wreg[j] = *(const float4*)&cw[(d0 + j) * 4];
        #pragma unroll
        for (int kk = 0; kk < 4; ++kk) {
            int li = l - 3 + kk;
            if (li >= 0) {
                int srow = br ? (b * LF + (LF - 1 - li)) : (b * LF + li);
                const float4* xp = (const float4*)&xz[(size_t)srow * 2 * DIN + d0];
                #pragma unroll
                for (int i = 0; i < 4; ++i) {
                    float4 x = xp[i];
                    a16[4 * i]     += x.x * wreg[4 * i][kk];
                    a16[4 * i + 1] += x.y * wreg[4 * i + 1][kk];
                    a16[4 * i + 2] += x.z * wreg[4 * i + 2][kk];
                    a16[4 * i + 3] += x.w * wreg[4 * i + 3][kk];
                }
            }
        }
        #pragma unroll
        for (int j = 0; j < 16; ++j) a16[j] = siluf(a16[j]);
    } else {
        #pragma unroll
        for (int j = 0; j < 16; ++j) a16[j] = 0.f;
    }

    // ---- W fragment (16 k-values for row m_s) ----
    float4 pw[4];
    {
        const float4 z4 = make_float4(0.f, 0.f, 0.f, 0.f);
        if (m_s < XDB) {
            const float4* src = (const float4*)&W[(size_t)m_s * DIN + kb + q_s * 16];
            pw[0] = src[0]; pw[1] = src[1]; pw[2] = src[2]; pw[3] = src[3];
        } else { pw[0] = z4; pw[1] = z4; pw[2] = z4; pw[3] = z4; }
    }

    auto cvt8a = [&](int o) -> short8 {
        short8 r;
        #pragma unroll
        for (int j = 0; j < 8; ++j) r[j] = f2bf(a16[o + j]);
        return r;
    };
    auto cvt8w = [&](float4 a, float4 b) -> short8 {
        short8 r;
        r[0] = f2bf(a.x); r[1] = f2bf(a.y); r[2] = f2bf(a.z); r[3] = f2bf(a.w);
        r[4] = f2bf(b.x); r[5] = f2bf(b.y); r[6] = f2bf(b.z); r[7] = f2bf(b.w);
        return r;
    };

    *(short8*)&Ash[((2 * q_s) * 64 + m_s) * 8]     = cvt8a(0);
    *(short8*)&Ash[((2 * q_s + 1) * 64 + m_s) * 8] = cvt8a(8);
    *(short8*)&Wsh[((2 * q_s) * 64 + m_s) * 8]     = cvt8w(pw[0], pw[1]);
    *(short8*)&Wsh[((2 * q_s + 1) * 64 + m_s) * 8] = cvt8w(pw[2], pw[3]);
    if (mok) {  // side-product: materialize xc for the scan kernels
        float4* dst = (float4*)&xco[(size_t)m * DIN + d0];
        dst[0] = make_float4(a16[0], a16[1], a16[2], a16[3]);
        dst[1] = make_float4(a16[4], a16[5], a16[6], a16[7]);
        dst[2] = make_float4(a16[8], a16[9], a16[10], a16[11]);
        dst[3] = make_float4(a16[12], a16[13], a16[14], a16[15]);
    }
    __syncthreads();

    f32x4 acc[2][2];
    #pragma unroll
    for (int i = 0; i < 2; ++i)
        #pragma unroll
        for (int j = 0; j < 2; ++j)
            acc[i][j] = f32x4{0.f, 0.f, 0.f, 0.f};

    #pragma unroll
    for (int kh = 0; kh < 2; ++kh) {
        const int kg = kh * 4 + qq;
        short8 af0 = *(const short8*)&Ash[(kg * 64 + wm + lr) * 8];
        short8 af1 = *(const short8*)&Ash[(kg * 64 + wm + 16 + lr) * 8];
        short8 wf0 = *(const short8*)&Wsh[(kg * 64 + wn + lr) * 8];
        short8 wf1 = *(const short8*)&Wsh[(kg * 64 + wn + 16 + lr) * 8];
        acc[0][0] = __builtin_amdgcn_mfma_f32_16x16x32_bf16(af0, wf0, acc[0][0], 0, 0, 0);
        acc[0][1] = __builtin_amdgcn_mfma_f32_16x16x32_bf16(af0, wf1, acc[0][1], 0, 0, 0);
        acc[1][0] = __builtin_amdgcn_mfma_f32_16x16x32_bf16(af1, wf0, acc[1][0], 0, 0, 0);
        acc[1][1] = __builtin_amdgcn_mfma_f32_16x16x32_bf16(af1, wf1, acc[1][1], 0, 0, 0);
    }

    #pragma unroll
    for (int mi = 0; mi < 2; ++mi) {
        #pragma unroll
        for (int ni = 0; ni < 2; ++ni) {
            int col = wn + ni * 16 + lr;
            if (col >= XDB) continue;
            #pragma unroll
            for (int r = 0; r < 4; ++r) {
                int row = bm + wm + mi * 16 + qq * 4 + r;
                if (row >= MR) continue;
                atomicAdd(&xdo[(size_t)row * XDB + col], acc[mi][ni][r]);
            }
        }
    }
}

// cls row: residual[b, 128, :] = cls + pos[128]
__global__ void cls_k(const float* __restrict__ cls, const float* __restrict__ pos,
                      float* __restrict__ residual) {
    int b = blockIdx.x, t = threadIdx.x;
    residual[(size_t)(b * LF + POSROW) * DMODEL + t] =
        cls[t] + pos[(size_t)POSROW * DMODEL + t];
}

// row-wise layernorm STATS over 384 -> (mean, rstd) per row
__global__ __launch_bounds__(128) void lnstat_k(const float* __restrict__ X,
                                                float2* __restrict__ st) {
    int r = blockIdx.x;
    const float* x = X + (size_t)r * DMODEL;
    int t = threadIdx.x;
    float v0 = x[t], v1 = x[t + 128], v2 = x[t + 256];
    float s = v0 + v1 + v2;
    float sq = v0 * v0 + v1 * v1 + v2 * v2;
    #pragma unroll
    for (int o = 32; o > 0; o >>= 1) {
        s += __shfl_down(s, o);
        sq += __shfl_down(sq, o);
    }
    __shared__ float ls[2], lq[2];
    if ((t & 63) == 0) { ls[t >> 6] = s; lq[t >> 6] = sq; }
    __syncthreads();
    if (t == 0) {
        float S = ls[0] + ls[1], Q = lq[0] + lq[1];
        float mean = S * (1.f / 384.f);
        float var = Q * (1.f / 384.f) - mean * mean;
        st[r] = make_float2(mean, rsqrtf(var + 1e-5f));
    }
}

// ---------------------------------------------------------------------------
// Chunked scan (CL=16), SPLIT-NST: 2 paired lanes per d-column, 8 states each.
// scanA materializes dt; scanC consumes it (dt-handoff) and prefix-combines
// with the suffix-sum trick (serial chain = 1 add per chunk).
// ---------------------------------------------------------------------------
__global__ __launch_bounds__(256) void scanA_k(
    const float* __restrict__ xcf, const float* __restrict__ xcb,
    const float* __restrict__ xdbf, const float* __restrict__ xdbb,
    const float* __restrict__ alf, const float* __restrict__ alb,
    const float* __restrict__ dwf, const float* __restrict__ dbf,
    const float* __restrict__ dwb, const float* __restrict__ dbb,
    float* __restrict__ hpart, float* __restrict__ sumd,
    float* __restrict__ dtf, float* __restrict__ dtb) {
    const int t = threadIdx.x;
    const int half = t & 1, dl = t >> 1;
    const int y = blockIdx.y;            // b*2+br
    const int b = y >> 1, br = y & 1;
    const int c = blockIdx.z;
    const int d = blockIdx.x * 128 + dl;
    const float* xc  = br ? xcb  : xcf;
    const float* xdb = br ? xdbb : xdbf;
    const float* Al  = br ? alb  : alf;
    const float* dw  = br ? dwb  : dwf;
    const float* dbi = br ? dbb  : dbf;
    float* dto       = br ? dtb  : dtf;

    float An[8];
    #pragma unroll
    for (int n = 0; n < 8; ++n)
        An[n] = -__expf(Al[(size_t)d * NST + half * 8 + n]);
    float wdt[DTR];
    #pragma unroll
    for (int k = 0; k < DTR; k += 4)
        *(float4*)&wdt[k] = *(const float4*)&dw[(size_t)d * DTR + k];
    float dbv = dbi[d];

    // batch-prefetch xc values for all CL steps (independent loads)
    float xr[CL];
    #pragma unroll
    for (int s = 0; s < CL; ++s) {
        int l = c * CL + s;
        xr[s] = (l < LF) ? xc[(size_t)(b * LF + l) * DIN + d] : 0.f;
    }

    __shared__ float sXD[CL][DTR];
    __shared__ float sB[CL][NST];
    for (int idx = t; idx < CL * DTR; idx += 256) {
        int s0 = idx / DTR, j0 = idx - s0 * DTR;
        int l0 = c * CL + s0;
        sXD[s0][j0] = (l0 < LF) ? xdb[(size_t)(b * LF + l0) * XDB + j0] : 0.f;
    }
    {
        int s0 = t >> 4, j0 = t & 15;
        int l0 = c * CL + s0;
        sB[s0][j0] = (l0 < LF) ? xdb[(size_t)(b * LF + l0) * XDB + DTR + j0] : 0.f;
    }
    __syncthreads();

    float h[8] = {};
    float sdt = 0.f;
    #pragma unroll
    for (int s = 0; s < CL; ++s) {
        int l = c * CL + s;
        if (l < LF) {
            float dtv = dbv;
            #pragma unroll
            for (int k = 0; k < DTR; ++k) dtv += sXD[s][k] * wdt[k];
            dtv = softplusf(dtv);
            if (half == 0) dto[(size_t)(b * LF + l) * DIN + d] = dtv;
            sdt += dtv;
            float dtx = dtv * xr[s];
            #pragma unroll
            for (int n = 0; n < 8; ++n)
                h[n] = __expf(dtv * An[n]) * h[n] + dtx * sB[s][half * 8 + n];
        }
    }
    size_t base = (size_t)(c * 8 + y) * NST;
    #pragma unroll
    for (int n = 0; n < 8; ++n)
        hpart[(base + half * 8 + n) * DIN + d] = h[n];
    if (half == 0) sumd[(size_t)(c * 8 + y) * DIN + d] = sdt;
}

__global__ __launch_bounds__(256) void scanC_k(
    const float* __restrict__ xcf, const float* __restrict__ xcb,
    const float* __restrict__ xdbf, const float* __restrict__ xdbb,
    const float* __restrict__ xz,
    const float* __restrict__ alf, const float* __restrict__ dpf,
    const float* __restrict__ alb, const float* __restrict__ dpb,
    const float* __restrict__ dtf, const float* __restrict__ dtb,
    const float* __restrict__ hpart, const float* __restrict__ sumd,
    float* __restrict__ yf, float* __restrict__ yb) {
    const int t = threadIdx.x;
    const int half = t & 1, dl = t >> 1;
    const int y = blockIdx.y;
    const int b = y >> 1, br = y & 1;
    const int c = blockIdx.z;
    const int d = blockIdx.x * 128 + dl;
    const float* xc  = br ? xcb  : xcf;
    const float* xdb = br ? xdbb : xdbf;
    const float* Al  = br ? alb  : alf;
    const float* Dpp = br ? dpb  : dpf;
    const float* dti = br ? dtb  : dtf;
    float* yo        = br ? yb   : yf;

    float An[8];
    #pragma unroll
    for (int n = 0; n < 8; ++n)
        An[n] = -__expf(Al[(size_t)d * NST + half * 8 + n]);
    float Dv = Dpp[d];

    // batch-prefetch dt, xc and z values for all CL steps (independent loads)
    float dtr[CL], xr[CL], zr[CL];
    #pragma unroll
    for (int s = 0; s < CL; ++s) {
        int l = c * CL + s;
        if (l < LF) {
            size_t rowoff = (size_t)(b * LF + l) * DIN + d;
            dtr[s] = dti[rowoff];
            xr[s] = xc[rowoff];
            int zl = br ? (LF - 1 - l) : l;
            zr[s] = xz[(size_t)(b * LF + zl) * (2 * DIN) + DIN + d];
        } else { dtr[s] = 0.f; xr[s] = 0.f; zr[s] = 0.f; }
    }

    __shared__ float sB[CL][NST];
    __shared__ float sC[CL][NST];
    {
        int s0 = t >> 4, j0 = t & 15;
        int l0 = c * CL + s0;
        size_t rb = (size_t)(b * LF + l0) * XDB + DTR;
        sB[s0][j0] = (l0 < LF) ? xdb[rb + j0] : 0.f;
        sC[s0][j0] = (l0 < LF) ? xdb[rb + NST + j0] : 0.f;
    }
    __syncthreads();

    // prefix-combine earlier chunks, DESCENDING with running suffix-sum:
    // h[n] = sum_j exp(An*S_j)*hp_j[n], S_j = sum_{j'>j} sd_{j'}.
    // Serial chain is one add per j; loads/exps are independent.
    float h[8] = {};
    float suf = 0.f;
    for (int j = c - 1; j >= 0; --j) {
        float sd = sumd[(size_t)(j * 8 + y) * DIN + d];
        size_t bj = (size_t)(j * 8 + y) * NST;
        #pragma unroll
        for (int n = 0; n < 8; ++n)
            h[n] += __expf(An[n] * suf) * hpart[(bj + half * 8 + n) * DIN + d];
        suf += sd;
    }

    #pragma unroll
    for (int s = 0; s < CL; ++s) {
        int l = c * CL + s;
        if (l < LF) {
            int row = b * LF + l;
            float dtv = dtr[s];
            float dtx = dtv * xr[s];
            float acc = 0.f;
            #pragma unroll
            for (int n = 0; n < 8; ++n) {
                h[n] = __expf(dtv * An[n]) * h[n] + dtx * sB[s][half * 8 + n];
                acc += h[n] * sC[s][half * 8 + n];
            }
            acc += __shfl_xor(acc, 1);   // combine the two halves' partial sums
            if (half == 0)
                yo[(size_t)row * DIN + d] = (acc + xr[s] * Dv) * siluf(zr[s]);
        }
    }
}

// final LN(row POS) + command MLP + add -> f32 out
__global__ __launch_bounds__(384) void final_k(
    const float* __restrict__ residual,
    const float* __restrict__ lnw, const float* __restrict__ lnb,
    const float* __restrict__ sv, const float* __restrict__ act,
    const float* __restrict__ cw1, const float* __restrict__ cb1,
    const float* __restrict__ cw2, const float* __restrict__ cb2,
    float* __restrict__ out) {
    int b = blockIdx.x, t = threadIdx.x;
    const float* x = residual + (size_t)(b * LF + POSROW) * DMODEL;
    float v = x[t];
    float s = v, sq = v * v;
    #pragma unroll
    for (int o = 32; o > 0; o >>= 1) {
        s += __shfl_down(s, o);
        sq += __shfl_down(sq, o);
    }
    __shared__ float ls[6], lq[6], hid[DMODEL], cmdin[20];
    if ((t & 63) == 0) { ls[t >> 6] = s; lq[t >> 6] = sq; }
    if (t < 20) cmdin[t] = (t < 16) ? sv[b * 16 + t] : act[b * 4 + t - 16];
    __syncthreads();
    float S = 0.f, Q = 0.f;
    #pragma unroll
    for (int w = 0; w < 6; ++w) { S += ls[w]; Q += lq[w]; }
    float mean = S * (1.f / 384.f);
    float var = Q * (1.f / 384.f) - mean * mean;
    float rs = rsqrtf(var + 1e-5f);
    float vis = (v - mean) * rs * lnw[t] + lnb[t];
    float a1 = cb1[t];
    #pragma unroll
    for (int k = 0; k < 20; ++k) a1 += cmdin[k] * cw1[t * 20 + k];
    hid[t] = fmaxf(a1, 0.f);
    __syncthreads();
    float a2 = cb2[t];
    for (int k = 0; k < DMODEL; ++k) a2 += hid[k] * cw2[t * DMODEL + k];
    out[b * DMODEL + t] = vis + a2;
}

extern "C" void kernel_launch(void* const* d_in, const int* in_sizes, int n_in,
                              void* d_out, int out_size, void* d_ws, size_t ws_size,
                              hipStream_t stream) {
    const float* depth_seq = (const float*)d_in[0];
    const float* state_vec = (const float*)d_in[1];
    const float* action    = (const float*)d_in[2];
    const float* patch_w   = (const float*)d_in[3];
    const float* patch_b   = (const float*)d_in[4];
    const float* cls_token = (const float*)d_in[5];
    const float* pos_embed = (const float*)d_in[6];
    const float* ln_w      = (const float*)d_in[7];
    const float* ln_b      = (const float*)d_in[8];
    const float* in_proj_w = (const float*)d_in[9];
    const float* conv_w    = (const float*)d_in[10];
    const float* conv_b    = (const float*)d_in[11];
    const float* conv_wb   = (const float*)d_in[12];
    const float* conv_bb   = (const float*)d_in[13];
    const float* xproj_w   = (const float*)d_in[14];
    const float* xproj_wb  = (const float*)d_in[15];
    const float* dtproj_w  = (const float*)d_in[16];
    const float* dtproj_b  = (const float*)d_in[17];
    const float* dtproj_wb = (const float*)d_in[18];
    const float* dtproj_bb = (const float*)d_in[19];
    const float* A_log     = (const float*)d_in[20];
    const float* A_logb    = (const float*)d_in[21];
    const float* Dp        = (const float*)d_in[22];
    const float* Dpb       = (const float*)d_in[23];
    const float* out_w     = (const float*)d_in[24];
    const float* lnf_w     = (const float*)d_in[25];
    const float* lnf_b     = (const float*)d_in[26];
    const float* cw1       = (const float*)d_in[27];
    const float* cb1       = (const float*)d_in[28];
    const float* cw2       = (const float*)d_in[29];
    const float* cb2       = (const float*)d_in[30];

    float* ws = (float*)d_ws;
    size_t o = 0;
    float* residual = ws + o; o += (size_t)MR * DMODEL;
    float* xz       = ws + o; o += (size_t)MR * 2 * DIN;
    float* xcf      = ws + o; o += (size_t)MR * DIN;
    float* xcb      = ws + o; o += (size_t)MR * DIN;
    float* xdbf     = ws + o; o += (size_t)MR * XDB;   // adjacent pair:
    float* xdbb     = ws + o; o += (size_t)MR * XDB;   // zeroed by in_proj
    float* yfb      = ws + o; o += (size_t)MR * DIN;
    float* ybb      = ws + o; o += (size_t)MR * DIN;
    float* hpart    = ws + o; o += (size_t)NC * 8 * NST * DIN;
    float* sumd     = ws + o; o += (size_t)NC * 8 * DIN;
    float* dtf      = ws + o; o += (size_t)MR * DIN;   // dt handoff (fwd)
    float* dtb      = ws + o; o += (size_t)MR * DIN;   // dt handoff (bwd)
    float2* stats   = (float2*)(ws + o); o += (size_t)MR * 2;
    (void)ws_size; (void)in_sizes; (void)n_in; (void)out_size;

    // patchify -> residual (bias + pos, cls gap), MFMA, K64 x 4 steps
    mgemm_k<1, 3, 64, 2><<<dim3(16, 6), 256, 0, stream>>>(
        nullptr, 0, patch_w, patch_b, residual, 1024, DMODEL, 256, 1,
        depth_seq, nullptr, pos_embed, nullptr, 0);
    cls_k<<<BB, DMODEL, 0, stream>>>(cls_token, pos_embed, residual);

    for (int i = 0; i < 4; ++i) {
        // LN stats: one pass per layer
        lnstat_k<<<MR, 128, 0, stream>>>(residual, stats);
        // in_proj with fused LN, K64 x 6 steps; also zeroes xdb for xp_k
        mgemm_k<3, 0, 64, 2><<<dim3(17, 24), 256, 0, stream>>>(
            residual, DMODEL, in_proj_w + (size_t)i * 2 * DIN * DMODEL, nullptr,
            xz, MR, 2 * DIN, DMODEL, 1,
            (const float*)stats, ln_w + (size_t)i * DMODEL, ln_b + (size_t)i * DMODEL,
            xdbf, 2 * MR * XDB);
        // fused conv+SiLU + xproj (single K64 stage per block, NKC=12)
        xp_k<<<dim3(17, NKC, 2), 256, 0, stream>>>(
            xz, conv_w + (size_t)i * DIN * 4, conv_b + (size_t)i * DIN,
            conv_wb + (size_t)i * DIN * 4, conv_bb + (size_t)i * DIN,
            xproj_w + (size_t)i * XDB * DIN, xproj_wb + (size_t)i * XDB * DIN,
            xcf, xcb, xdbf, xdbb);
        // chunked scan (CL=16): scanA materializes dt, scanC consumes it
        scanA_k<<<dim3(6, 8, NC), 256, 0, stream>>>(
            xcf, xcb, xdbf, xdbb,
            A_log + (size_t)i * DIN * NST, A_logb + (size_t)i * DIN * NST,
            dtproj_w + (size_t)i * DIN * DTR, dtproj_b + (size_t)i * DIN,
            dtproj_wb + (size_t)i * DIN * DTR, dtproj_bb + (size_t)i * DIN,
            hpart, sumd, dtf, dtb);
        scanC_k<<<dim3(6, 8, NC), 256, 0, stream>>>(
            xcf, xcb, xdbf, xdbb, xz,
            A_log + (size_t)i * DIN * NST, Dp + (size_t)i * DIN,
            A_logb + (size_t)i * DIN * NST, Dpb + (size_t)i * DIN,
            dtf, dtb, hpart, sumd, yfb, ybb);
        // out_proj flip-add, split-K 4, K64 x 3 steps (dbuf), atomicAdd
        mgemm_k<2, 4, 64, 2><<<dim3(17, 6 * 4), 256, 0, stream>>>(
            yfb, DIN, out_w + (size_t)i * DMODEL * DIN, nullptr,
            residual, MR, DMODEL, DIN, 4, nullptr, ybb, nullptr, nullptr, 0);
    }

    final_k<<<BB, DMODEL, 0, stream>>>(
        residual, lnf_w, lnf_b, state_vec, action, cw1, cb1, cw2, cb2,
        (float*)d_out);
}